// Round 6
// baseline (22066.595 us; speedup 1.0000x reference)
//
#include <hip/hip_runtime.h>
#include <math.h>

#define NB 64
#define NT 1024
#define NI 128
#define NH 512

typedef unsigned long long u64;

// ---------------------------------------------------------------------------
// prep: transpose input-proj weights to k-major [k][j*4+m]; init tagged h
// buffer (both parities): tag=0, value=1.0f.
// ---------------------------------------------------------------------------
__global__ __launch_bounds__(256) void prep_kernel(
    const float* __restrict__ Wsw, const float* __restrict__ Wsm,
    const float* __restrict__ Wss, const float* __restrict__ Wtcx,
    float* __restrict__ WT_in, u64* __restrict__ htag)
{
  int idx = blockIdx.x * blockDim.x + threadIdx.x;
  int np  = gridDim.x * blockDim.x;
  for (int i = idx; i < NH * NI; i += np) {
    int j = i >> 7, k = i & 127;            // W is [H][I] row-major
    int o = k * 2048 + j * 4;
    WT_in[o + 0] = Wsw[i];
    WT_in[o + 1] = Wsm[i];
    WT_in[o + 2] = Wss[i];
    WT_in[o + 3] = Wtcx[i];
  }
  // {tag=0, 1.0f} in both parity halves
  for (int i = idx; i < 2 * NB * NH; i += np) htag[i] = 0x3F800000ULL;
}

// ---------------------------------------------------------------------------
// phase1: sensory + tcx for all (b,t).  Block = 32 rows x all 512 j.
// ---------------------------------------------------------------------------
__global__ __launch_bounds__(256, 2) void phase1_kernel(
    const float* __restrict__ x, const float* __restrict__ WT_in,
    const float* __restrict__ bsw, const float* __restrict__ bsm,
    const float* __restrict__ bss, const float* __restrict__ btc,
    float* __restrict__ sens, float* __restrict__ tcx)
{
  __shared__ __align__(16) float xs[32 * NI];   // 16 KB
  const int tid = threadIdx.x;
  const int n0  = blockIdx.x * 32;

  const float4* xsrc = (const float4*)(x + (size_t)n0 * NI);
#pragma unroll
  for (int i = 0; i < 4; i++)
    ((float4*)xs)[i * 256 + tid] = xsrc[i * 256 + tid];
  __syncthreads();

  for (int jj = 0; jj < 2; jj++) {
    const int j = tid + jj * 256;
    float4 acc[32];
#pragma unroll
    for (int n = 0; n < 32; n++) acc[n] = make_float4(0.f, 0.f, 0.f, 0.f);

    const float4* wp = (const float4*)WT_in + j;   // row k at wp[k*512]
#pragma unroll 2
    for (int k = 0; k < NI; k++) {
      float4 w = wp[(size_t)k * 512];
#pragma unroll
      for (int n = 0; n < 32; n++) {
        float xv = xs[n * NI + k];
        acc[n].x = fmaf(xv, w.x, acc[n].x);
        acc[n].y = fmaf(xv, w.y, acc[n].y);
        acc[n].z = fmaf(xv, w.z, acc[n].z);
        acc[n].w = fmaf(xv, w.w, acc[n].w);
      }
    }
    const float b0 = bsw[j], b1 = bsm[j], b2v = bss[j], b3 = btc[j];
#pragma unroll 4
    for (int n = 0; n < 32; n++) {
      float sw = acc[n].x + b0;
      float sm = acc[n].y + b1;
      float ss = acc[n].z + b2v;
      float tc = acc[n].w + b3;
      float sig = 1.f / (1.f + expf(-sm));
      float se  = expf(fminf(ss, 50.f));
      size_t o = (size_t)(n0 + n) * NH + j;
      sens[o] = sw * sig * se;
      tcx[o]  = tc;
    }
  }
}

// ---------------------------------------------------------------------------
// phase2: persistent recurrent scan with TWO INTERLEAVED BATCH-CHAINS per
// block.
//
// Ledger: r0 (tag-poll) 7.6 us/step, r3 (counter+data-once) 7.3, r1 (2
// waves/SIMD) worse, r5 (XCD-L2 fast path) dead -> the step cost is a
// SERIAL LATENCY CHAIN (publish-visibility ~1us + detect + transfer ~1us
// + compute ~2.2us), not poll volume, not detection granularity, not
// per-CU issue bandwidth.
//
// Fix: batches are independent recurrences.  128 blocks = 4 pair-cliques
// x 32 j-slices; each block keeps the proven r0 phase shape (16 j,
// wreg[4][32], 8 batches) but serves TWO batch-groups bgA=pc, bgB=pc+4,
// alternating within each t-iteration:
//   check A(t) [gather issued last iter] -> ISSUE B(t) gather ->
//   compute+publish A(t+1) -> check B(t) -> ISSUE A(t+1) gather ->
//   compute+publish B(t+1)
// Each chain's publish->visible->transfer latency hides under the other
// chain's ~1.1us compute phase.  Per-advanced-step exchange volume and
// VALU work are UNCHANGED; only the exposed latency is shared.
//
// Correctness: each chain is verbatim the r0 fence-free tagged protocol —
// publishing {t+1,h} data-depends on ALL of the block's tag-t reads for
// that chain, so parity double-buffering is race-free with no ordering
// primitives; tags gate every word (early gathers that catch stale words
// just re-poll at check time).  Chains use disjoint buffer regions.
// ---------------------------------------------------------------------------
#define ISSUE16(W, SRC)                                                     \
  _Pragma("unroll")                                                         \
  for (int i = 0; i < 16; i++)                                              \
    W[i] = __hip_atomic_load((SRC) + i * 256 + tid, __ATOMIC_RELAXED,       \
                             __HIP_MEMORY_SCOPE_AGENT);

#define CHECK16(W, SRC, WANT)                                               \
  for (;;) {                                                                \
    bool ok = true;                                                         \
    _Pragma("unroll")                                                       \
    for (int i = 0; i < 16; i++)                                            \
      ok = ok && ((unsigned)(W[i] >> 32) == (WANT));                        \
    if (ok) break;                                                          \
    __builtin_amdgcn_s_sleep(1);                                            \
    _Pragma("unroll")                                                       \
    for (int i = 0; i < 16; i++)                                            \
      if ((unsigned)(W[i] >> 32) != (WANT))                                 \
        W[i] = __hip_atomic_load((SRC) + i * 256 + tid, __ATOMIC_RELAXED,   \
                                 __HIP_MEMORY_SCOPE_AGENT);                 \
  }

// one full phase: scatter W into HL, dot, reduce, epilogue, publish to DST
#define DO_PHASE(HL, W, DST, EIDX, SENSV, TCXV, TP1)                        \
  {                                                                         \
    _Pragma("unroll")                                                       \
    for (int i = 0; i < 16; i++) {                                          \
      int f = i * 256 + tid;                                                \
      int b2 = f >> 9, k = f & 511;                                         \
      HL[b2 * 576 + (k >> 5) * 36 + (k & 31)] =                             \
          __uint_as_float((unsigned)(W[i] & 0xFFFFFFFFull));                \
    }                                                                       \
    __syncthreads();                                                        \
    float acc[4][8];                                                        \
    _Pragma("unroll")                                                       \
    for (int ci = 0; ci < 4; ci++)                                          \
      _Pragma("unroll")                                                     \
      for (int b2 = 0; b2 < 8; b2++) acc[ci][b2] = 0.f;                     \
    const float* hb = HL + r * 36;                                          \
    _Pragma("unroll")                                                       \
    for (int b2 = 0; b2 < 8; b2++) {                                        \
      _Pragma("unroll")                                                     \
      for (int kc = 0; kc < 32; kc += 4) {                                  \
        float4 hv = *(const float4*)(hb + b2 * 576 + kc);                   \
        _Pragma("unroll")                                                   \
        for (int ci = 0; ci < 4; ci++) {                                    \
          acc[ci][b2] = fmaf(wreg[ci][kc + 0], hv.x, acc[ci][b2]);          \
          acc[ci][b2] = fmaf(wreg[ci][kc + 1], hv.y, acc[ci][b2]);          \
          acc[ci][b2] = fmaf(wreg[ci][kc + 2], hv.z, acc[ci][b2]);          \
          acc[ci][b2] = fmaf(wreg[ci][kc + 3], hv.w, acc[ci][b2]);          \
        }                                                                   \
      }                                                                     \
    }                                                                       \
    _Pragma("unroll")                                                       \
    for (int ci = 0; ci < 4; ci++)                                          \
      _Pragma("unroll")                                                     \
      for (int b2 = 0; b2 < 8; b2++) {                                      \
        float v = acc[ci][b2];                                              \
        v += __shfl_xor(v, 16, 64);                                         \
        v += __shfl_xor(v, 32, 64);                                         \
        acc[ci][b2] = v;                                                    \
      }                                                                     \
    if (ln < 16) {                                                          \
      _Pragma("unroll")                                                     \
      for (int ci = 0; ci < 4; ci++)                                        \
        _Pragma("unroll")                                                   \
        for (int b2 = 0; b2 < 8; b2++)                                      \
          red[wv * 528 + ln * 33 + ci * 8 + b2] = acc[ci][b2];              \
    }                                                                       \
    float h_old = 0.f;                                                      \
    if (tid < 128) h_old = HL[eb * 576 + (ej >> 5) * 36 + (ej & 31)];       \
    __syncthreads();                                                        \
    if (tid < 128) {                                                        \
      float vals[4];                                                        \
      _Pragma("unroll")                                                     \
      for (int g2 = 0; g2 < 4; g2++) {                                      \
        int c = ejl * 4 + g2;                                               \
        int o = (c & 15) * 33 + (c >> 4) * 8 + eb;                          \
        vals[g2] = red[o] + red[528 + o] + red[1056 + o] + red[1584 + o];   \
      }                                                                     \
      float iwv = vals[0] + bw;                                             \
      float imv = vals[1] + bm;                                             \
      float isv = vals[2] + bs;                                             \
      float tch = vals[3];                                                  \
      float z   = (TCXV) + tch;                                             \
      float tau = fmaxf(z, 0.f) + log1pf(expf(-fabsf(z))) + 0.1f;           \
      float sig = 1.f / (1.f + expf(-imv));                                 \
      float inter = iwv * sig * expf(fminf(isv, 50.f));                     \
      float dh  = ((SENSV) + inter - h_old) / fmaxf(tau, 1e-8f);            \
      float hnew = h_old + 0.1f * dh;                                       \
      u64 nw = ((u64)(unsigned)(TP1) << 32) | (u64)__float_as_uint(hnew);   \
      __hip_atomic_store((DST) + eb * 512 + ej, nw, __ATOMIC_RELAXED,       \
                         __HIP_MEMORY_SCOPE_AGENT);                         \
      out[EIDX] = hnew;                                                     \
    }                                                                       \
  }

__global__ __launch_bounds__(256, 1) void phase2_kernel(
    const float* __restrict__ Wiw, const float* __restrict__ Wim,
    const float* __restrict__ Wis, const float* __restrict__ Wtch,
    const float* __restrict__ biw, const float* __restrict__ bim,
    const float* __restrict__ bis,
    const float* __restrict__ tcx, float* __restrict__ out,
    u64* __restrict__ htag)
{
  __shared__ __align__(16) float hlA[8 * 576];  // chain-A h tile (18 KB)
  __shared__ __align__(16) float hlB[8 * 576];  // chain-B h tile (18 KB)
  __shared__ float red[4 * 528];                // shared reduction scratch

  const int tid = threadIdx.x;
  const int wv  = tid >> 6;
  const int ln  = tid & 63;
  const int pc  = blockIdx.x & 3;     // pair-clique
  const int js  = blockIdx.x >> 2;    // j-slice 0..31
  const int bgA = pc;                 // batch-group of chain A
  const int bgB = pc + 4;             // batch-group of chain B

  const int cg = ln & 15;
  const int r  = wv * 4 + (ln >> 4);  // k-range id 0..15
  const int k0 = r << 5;

  // persistent weights (128 VGPRs): col c = cg + 16*ci, gate g = cg&3
  const int g   = cg & 3;
  const int jl0 = cg >> 2;
  const float* Wp = (g == 0) ? Wiw : (g == 1) ? Wim : (g == 2) ? Wis : Wtch;
  float wreg[4][32];
#pragma unroll
  for (int ci = 0; ci < 4; ci++) {
    const float* wrow = Wp + (size_t)(js * 16 + jl0 + 4 * ci) * NH + k0;
#pragma unroll
    for (int kk = 0; kk < 32; kk++) wreg[ci][kk] = wrow[kk];
  }

  // epilogue-thread constants (tid<128 handles (b = tid>>4, jl = tid&15))
  const int ejl = tid & 15;
  const int eb  = tid >> 4;
  const int ej  = js * 16 + ejl;
  float bw = 0.f, bm = 0.f, bs = 0.f;
  if (tid < 128) { bw = biw[ej]; bm = bim[ej]; bs = bis[ej]; }

  // chain buffers: parity p, group g at htag + p*NB*NH + g*4096
  u64* const hA0 = htag + bgA * 4096;
  u64* const hA1 = htag + NB * NH + bgA * 4096;
  u64* const hB0 = htag + bgB * 4096;
  u64* const hB1 = htag + NB * NH + bgB * 4096;

  // prologue: issue chain-A gather for t=0
  u64 wA[16], wB[16];
  ISSUE16(wA, hA0);

  for (int t = 0; t < NT; t++) {
    u64* sA = (t & 1) ? hA1 : hA0;
    u64* dA = (t & 1) ? hA0 : hA1;
    u64* sB = (t & 1) ? hB1 : hB0;
    u64* dB = (t & 1) ? hB0 : hB1;
    const unsigned want = (unsigned)t;

    // ---- prefetch sens/tcx for both chains (consumed in epilogues) ----
    float sensA = 0.f, tcxA = 0.f, sensB = 0.f, tcxB = 0.f;
    size_t eiA = 0, eiB = 0;
    if (tid < 128) {
      eiA   = ((size_t)(bgA * 8 + eb) * NT + t) * NH + ej;
      eiB   = ((size_t)(bgB * 8 + eb) * NT + t) * NH + ej;
      sensA = out[eiA];
      tcxA  = tcx[eiA];
      sensB = out[eiB];
      tcxB  = tcx[eiB];
    }

    // ---- chain A: check (issued last iter), then launch B's transfer ----
    CHECK16(wA, sA, want);
    ISSUE16(wB, sB);          // B's transfer flies under A's compute

    DO_PHASE(hlA, wA, dA, eiA, sensA, tcxA, t + 1);

    // ---- chain B: check, then launch A(t+1)'s transfer ----
    CHECK16(wB, sB, want);
    if (t + 1 < NT) ISSUE16(wA, dA);   // A(t+1) flies under B's compute

    DO_PHASE(hlB, wB, dB, eiB, sensB, tcxB, t + 1);
  }
}

// ---------------------------------------------------------------------------
extern "C" void kernel_launch(void* const* d_in, const int* in_sizes, int n_in,
                              void* d_out, int out_size, void* d_ws, size_t ws_size,
                              hipStream_t stream) {
  const float* x    = (const float*)d_in[0];
  const float* Wsw  = (const float*)d_in[1];
  const float* bsw  = (const float*)d_in[2];
  const float* Wsm  = (const float*)d_in[3];
  const float* bsm  = (const float*)d_in[4];
  const float* Wss  = (const float*)d_in[5];
  const float* bss  = (const float*)d_in[6];
  const float* Wiw  = (const float*)d_in[7];
  const float* biw  = (const float*)d_in[8];
  const float* Wim  = (const float*)d_in[9];
  const float* bim  = (const float*)d_in[10];
  const float* Wis  = (const float*)d_in[11];
  const float* bis  = (const float*)d_in[12];
  const float* Wtcx = (const float*)d_in[13];
  const float* Wtch = (const float*)d_in[14];
  const float* btc  = (const float*)d_in[15];
  float* out = (float*)d_out;

  // workspace (floats): WT_in[128*2048] | tcx[B*T*H] | htag[2*B*H u64]
  float* ws     = (float*)d_ws;
  float* WT_in  = ws;
  float* tcx    = ws + 262144;
  u64*   htag   = (u64*)(tcx + (size_t)NB * NT * NH);

  hipLaunchKernelGGL(prep_kernel, dim3(256), dim3(256), 0, stream,
                     Wsw, Wsm, Wss, Wtcx, WT_in, htag);

  hipLaunchKernelGGL(phase1_kernel, dim3(NB * NT / 32), dim3(256), 0, stream,
                     x, WT_in, bsw, bsm, bss, btc, out, tcx);

  hipLaunchKernelGGL(phase2_kernel, dim3(128), dim3(256), 0, stream,
                     Wiw, Wim, Wis, Wtch, biw, bim, bis,
                     tcx, out, htag);
}

// Round 8
// 7861.745 us; speedup vs baseline: 2.8068x; 2.8068x over previous
//
#include <hip/hip_runtime.h>
#include <math.h>

#define NB 64
#define NT 1024
#define NI 128
#define NH 512

typedef unsigned long long u64;

// ---------------------------------------------------------------------------
// prep: transpose input-proj weights to k-major [k][j*4+m]; init h data
// (both parities) to 1.0f and per-block step flags to 0.
// Visible to phase2 via end-of-kernel cache writeback (stream order).
// ---------------------------------------------------------------------------
__global__ __launch_bounds__(256) void prep_kernel(
    const float* __restrict__ Wsw, const float* __restrict__ Wsm,
    const float* __restrict__ Wss, const float* __restrict__ Wtcx,
    float* __restrict__ WT_in, float* __restrict__ hdat,
    unsigned* __restrict__ flg)
{
  int idx = blockIdx.x * blockDim.x + threadIdx.x;
  int np  = gridDim.x * blockDim.x;
  for (int i = idx; i < NH * NI; i += np) {
    int j = i >> 7, k = i & 127;            // W is [H][I] row-major
    int o = k * 2048 + j * 4;
    WT_in[o + 0] = Wsw[i];
    WT_in[o + 1] = Wsm[i];
    WT_in[o + 2] = Wss[i];
    WT_in[o + 3] = Wtcx[i];
  }
  for (int i = idx; i < 2 * NB * NH; i += np) hdat[i] = 1.0f;  // both parities
  for (int i = idx; i < 512; i += np) flg[i] = 0u;  // [2 parity][8 bg][32 js]
}

// ---------------------------------------------------------------------------
// phase1: sensory + tcx for all (b,t).  Block = 32 rows x all 512 j.
// ---------------------------------------------------------------------------
__global__ __launch_bounds__(256, 2) void phase1_kernel(
    const float* __restrict__ x, const float* __restrict__ WT_in,
    const float* __restrict__ bsw, const float* __restrict__ bsm,
    const float* __restrict__ bss, const float* __restrict__ btc,
    float* __restrict__ sens, float* __restrict__ tcx)
{
  __shared__ __align__(16) float xs[32 * NI];   // 16 KB
  const int tid = threadIdx.x;
  const int n0  = blockIdx.x * 32;

  const float4* xsrc = (const float4*)(x + (size_t)n0 * NI);
#pragma unroll
  for (int i = 0; i < 4; i++)
    ((float4*)xs)[i * 256 + tid] = xsrc[i * 256 + tid];
  __syncthreads();

  for (int jj = 0; jj < 2; jj++) {
    const int j = tid + jj * 256;
    float4 acc[32];
#pragma unroll
    for (int n = 0; n < 32; n++) acc[n] = make_float4(0.f, 0.f, 0.f, 0.f);

    const float4* wp = (const float4*)WT_in + j;   // row k at wp[k*512]
#pragma unroll 2
    for (int k = 0; k < NI; k++) {
      float4 w = wp[(size_t)k * 512];
#pragma unroll
      for (int n = 0; n < 32; n++) {
        float xv = xs[n * NI + k];
        acc[n].x = fmaf(xv, w.x, acc[n].x);
        acc[n].y = fmaf(xv, w.y, acc[n].y);
        acc[n].z = fmaf(xv, w.z, acc[n].z);
        acc[n].w = fmaf(xv, w.w, acc[n].w);
      }
    }
    const float b0 = bsw[j], b1 = bsm[j], b2v = bss[j], b3 = btc[j];
#pragma unroll 4
    for (int n = 0; n < 32; n++) {
      float sw = acc[n].x + b0;
      float sm = acc[n].y + b1;
      float ss = acc[n].z + b2v;
      float tc = acc[n].w + b3;
      float sig = 1.f / (1.f + expf(-sm));
      float se  = expf(fminf(ss, 50.f));
      size_t o = (size_t)(n0 + n) * NH + j;
      sens[o] = sw * sig * se;
      tcx[o]  = tc;
    }
  }
}

// ---------------------------------------------------------------------------
// phase2: persistent recurrent scan.  Round-3 structure (counter-flag
// exchange, data moves once, untagged) with the shared atomicAdd counter
// replaced by PER-BLOCK FLAGS — no atomic RMW anywhere.
//
// r3's residual ~4us/step unexplained by hop latencies has one O(clique)
// serial term: 32 atomicAdds to the SAME line arriving clustered, each an
// RMW serialized at the MALL (~200cy) -> ~2.7us on the critical path.
// Plain STORES to distinct words of a line merge at the MALL without
// serializing.  So:
//   Writers: publish untagged f32 h via agent-scope relaxed stores, drain
//   own vmcnt, __syncthreads, then tid0 does ONE plain agent-scope store
//   flag[parity][bg][js] = t+1.
//   Readers: lane-parallel poll (lane ln loads flag[ln&31], __all(v>=t)) —
//   one coalesced 128B load per round, no RMW, detect = 1 MALL round trip.
//
// Ordering/race-freedom (same as r3): flag visible => writer's h stores
// were drained to the coherence point before the flag store issued
// (vmcnt(0) + barrier precede it); reader's data loads are control-dep +
// compiler-fenced after the poll.  Parity: a block starts step t only
// after ALL blocks published h(t), which implies all step-(t-1) gathers
// finished -> overwriting parity(t+1) is race-free.  Flags are monotone
// per parity (fbg1: 1,3,5..; fbg0: 2,4,6..) -> `>= t` detection, no
// deadlock.  No XCD-placement assumptions.
// ---------------------------------------------------------------------------
__global__ __launch_bounds__(256, 1) void phase2_kernel(
    const float* __restrict__ Wiw, const float* __restrict__ Wim,
    const float* __restrict__ Wis, const float* __restrict__ Wtch,
    const float* __restrict__ biw, const float* __restrict__ bim,
    const float* __restrict__ bis,
    const float* __restrict__ tcx, float* __restrict__ out,
    float* __restrict__ hdat, unsigned* __restrict__ flg)
{
  __shared__ __align__(16) float hl[8 * 576];   // skewed h tile
  __shared__ float red[4 * 528];                // reduction scratch

  const int tid = threadIdx.x;
  const int wv  = tid >> 6;
  const int ln  = tid & 63;
  const int bg  = blockIdx.x & 7;
  const int js  = blockIdx.x >> 3;

  const int cg = ln & 15;
  const int r  = wv * 4 + (ln >> 4);   // k-range id 0..15
  const int k0 = r << 5;

  // persistent weights (128 VGPRs): col c = cg + 16*ci, gate g = cg&3
  const int g   = cg & 3;
  const int jl0 = cg >> 2;
  const float* Wp = (g == 0) ? Wiw : (g == 1) ? Wim : (g == 2) ? Wis : Wtch;
  float wreg[4][32];
#pragma unroll
  for (int ci = 0; ci < 4; ci++) {
    const float* wrow = Wp + (size_t)(js * 16 + jl0 + 4 * ci) * NH + k0;
#pragma unroll
    for (int kk = 0; kk < 32; kk++) wreg[ci][kk] = wrow[kk];
  }

  // epilogue-thread constants (tid<128 handles (b = tid>>4, jl = tid&15))
  const int ejl = tid & 15;
  const int eb  = tid >> 4;
  const int ej  = js * 16 + ejl;
  float bw = 0.f, bm = 0.f, bs = 0.f;
  if (tid < 128) { bw = biw[ej]; bm = bim[ej]; bs = bis[ej]; }

  float* const hp0 = hdat + bg * 4096;            // parity 0 (f32)
  float* const hp1 = hdat + NB * NH + bg * 4096;  // parity 1 (f32)
  unsigned* const fbg0 = flg + bg * 32;           // flags, parity 0
  unsigned* const fbg1 = flg + 256 + bg * 32;     // flags, parity 1

  for (int t = 0; t < NT; t++) {
    const u64* dsrc = (const u64*)((t & 1) ? hp1 : hp0);
    unsigned*  ddst = (unsigned*)((t & 1) ? hp0 : hp1);
    unsigned* fsrc = (t & 1) ? fbg1 : fbg0;
    unsigned* fdst = (t & 1) ? fbg0 : fbg1;
    const unsigned want = (unsigned)t;

    // ---- prefetch sens/tcx early (consumed in epilogue) ----
    float sens_v = 0.f, tcx_v = 0.f;
    size_t eidx = 0;
    if (tid < 128) {
      eidx   = ((size_t)(bg * 8 + eb) * NT + t) * NH + ej;
      sens_v = out[eidx];
      tcx_v  = tcx[eidx];
    }

    // ---- detection: lane-parallel flag poll (no RMW, 1 line) ----
    if (t > 0) {
      for (;;) {
        unsigned v = __hip_atomic_load(fsrc + (ln & 31), __ATOMIC_RELAXED,
                                       __HIP_MEMORY_SCOPE_AGENT);
        if (__all((int)(v >= want))) break;
        __builtin_amdgcn_s_sleep(1);
      }
      asm volatile("" ::: "memory");   // order data loads after the poll
    }

    // ---- data: 8 x 8B agent-scope loads per lane (16 KB/block, once) ----
    u64 w[8];
#pragma unroll
    for (int i = 0; i < 8; i++)
      w[i] = __hip_atomic_load(dsrc + i * 256 + tid, __ATOMIC_RELAXED,
                               __HIP_MEMORY_SCOPE_AGENT);

    // ---- scatter to skewed LDS tile (float2 per word) ----
#pragma unroll
    for (int i = 0; i < 8; i++) {
      int f  = i * 256 + tid;          // u64 index: b2 = f>>8, kpair = f&255
      int b2 = f >> 8;
      int k  = (f & 255) << 1;         // even k
      float lo = __uint_as_float((unsigned)(w[i] & 0xFFFFFFFFull));
      float hi = __uint_as_float((unsigned)(w[i] >> 32));
      *(float2*)&hl[b2 * 576 + (k >> 5) * 36 + (k & 31)] = make_float2(lo, hi);
    }
    __syncthreads();   // (A) tile visible; also protects red[] across steps

    // ---- partial dots: 4 cols x 8 batches over 32 k ----
    float acc[4][8];
#pragma unroll
    for (int ci = 0; ci < 4; ci++)
#pragma unroll
      for (int b2 = 0; b2 < 8; b2++) acc[ci][b2] = 0.f;

    const float* hb = hl + r * 36;
#pragma unroll
    for (int b2 = 0; b2 < 8; b2++) {
#pragma unroll
      for (int kc = 0; kc < 32; kc += 4) {
        float4 hv = *(const float4*)(hb + b2 * 576 + kc);
#pragma unroll
        for (int ci = 0; ci < 4; ci++) {
          acc[ci][b2] = fmaf(wreg[ci][kc + 0], hv.x, acc[ci][b2]);
          acc[ci][b2] = fmaf(wreg[ci][kc + 1], hv.y, acc[ci][b2]);
          acc[ci][b2] = fmaf(wreg[ci][kc + 2], hv.z, acc[ci][b2]);
          acc[ci][b2] = fmaf(wreg[ci][kc + 3], hv.w, acc[ci][b2]);
        }
      }
    }

    // ---- reduce over 16 k-ranges ----
#pragma unroll
    for (int ci = 0; ci < 4; ci++)
#pragma unroll
      for (int b2 = 0; b2 < 8; b2++) {
        float v = acc[ci][b2];
        v += __shfl_xor(v, 16, 64);
        v += __shfl_xor(v, 32, 64);
        acc[ci][b2] = v;
      }
    if (ln < 16) {
#pragma unroll
      for (int ci = 0; ci < 4; ci++)
#pragma unroll
        for (int b2 = 0; b2 < 8; b2++)
          red[wv * 528 + ln * 33 + ci * 8 + b2] = acc[ci][b2];
    }
    // h_old read BEFORE barrier (B): hl stays untouched until after (B)
    float h_old = 0.f;
    if (tid < 128) h_old = hl[eb * 576 + (ej >> 5) * 36 + (ej & 31)];
    __syncthreads();   // (B) red visible

    // ---- epilogue: 128 (b,j) pairs ----
    if (tid < 128) {
      float vals[4];
#pragma unroll
      for (int g2 = 0; g2 < 4; g2++) {
        int c = ejl * 4 + g2;
        int o = (c & 15) * 33 + (c >> 4) * 8 + eb;
        vals[g2] = red[o] + red[528 + o] + red[1056 + o] + red[1584 + o];
      }
      float iwv = vals[0] + bw;
      float imv = vals[1] + bm;
      float isv = vals[2] + bs;
      float tch = vals[3];
      float z   = tcx_v + tch;
      float tau = fmaxf(z, 0.f) + log1pf(expf(-fabsf(z))) + 0.1f;  // softplus+0.1
      float sig = 1.f / (1.f + expf(-imv));
      float inter = iwv * sig * expf(fminf(isv, 50.f));
      float dh  = (sens_v + inter - h_old) / fmaxf(tau, 1e-8f);
      float hnew = h_old + 0.1f * dh;
      // publish h (agent scope, MALL), then out (plain)
      __hip_atomic_store(ddst + eb * 512 + ej, __float_as_uint(hnew),
                         __ATOMIC_RELAXED, __HIP_MEMORY_SCOPE_AGENT);
      out[eidx] = hnew;                              // overwrite sens in place
      asm volatile("s_waitcnt vmcnt(0)" ::: "memory");  // own stores at MALL
    }
    __syncthreads();   // (C) all 128 h-stores drained before the flag store
    if (tid == 0)
      __hip_atomic_store(fdst + js, (unsigned)(t + 1), __ATOMIC_RELAXED,
                         __HIP_MEMORY_SCOPE_AGENT);   // plain store, no RMW
  }
}

// ---------------------------------------------------------------------------
extern "C" void kernel_launch(void* const* d_in, const int* in_sizes, int n_in,
                              void* d_out, int out_size, void* d_ws, size_t ws_size,
                              hipStream_t stream) {
  const float* x    = (const float*)d_in[0];
  const float* Wsw  = (const float*)d_in[1];
  const float* bsw  = (const float*)d_in[2];
  const float* Wsm  = (const float*)d_in[3];
  const float* bsm  = (const float*)d_in[4];
  const float* Wss  = (const float*)d_in[5];
  const float* bss  = (const float*)d_in[6];
  const float* Wiw  = (const float*)d_in[7];
  const float* biw  = (const float*)d_in[8];
  const float* Wim  = (const float*)d_in[9];
  const float* bim  = (const float*)d_in[10];
  const float* Wis  = (const float*)d_in[11];
  const float* bis  = (const float*)d_in[12];
  const float* Wtcx = (const float*)d_in[13];
  const float* Wtch = (const float*)d_in[14];
  const float* btc  = (const float*)d_in[15];
  float* out = (float*)d_out;

  // workspace (floats): WT_in[128*2048] | tcx[B*T*H] |
  //                     hdat[2*B*H f32] | flg[512 u32]
  float* ws     = (float*)d_ws;
  float* WT_in  = ws;
  float* tcx    = ws + 262144;
  float* hdat   = tcx + (size_t)NB * NT * NH;
  unsigned* flg = (unsigned*)(hdat + 2 * NB * NH);

  hipLaunchKernelGGL(prep_kernel, dim3(256), dim3(256), 0, stream,
                     Wsw, Wsm, Wss, Wtcx, WT_in, hdat, flg);

  hipLaunchKernelGGL(phase1_kernel, dim3(NB * NT / 32), dim3(256), 0, stream,
                     x, WT_in, bsw, bsm, bss, btc, out, tcx);

  hipLaunchKernelGGL(phase2_kernel, dim3(256), dim3(256), 0, stream,
                     Wiw, Wim, Wis, Wtch, biw, bim, bis,
                     tcx, out, hdat, flg);
}